// Round 2
// baseline (528.737 us; speedup 1.0000x reference)
//
#include <hip/hip_runtime.h>
#include <hip/hip_bf16.h>
#include <stdint.h>

typedef __bf16 bf16_t;
typedef __bf16 bf16x8 __attribute__((ext_vector_type(8)));
typedef float  f32x4  __attribute__((ext_vector_type(4)));

#define B_   4
#define S_   2048
#define D_   1024
#define H_   16
#define DH_  64
#define MTOT (B_ * S_)   // 8192

// ---------------------------------------------------------------- utilities
__device__ __forceinline__ void gload_lds16(const void* g, void* l) {
  // direct global->LDS, 16B per lane; LDS dest = wave-uniform base + lane*16
  __builtin_amdgcn_global_load_lds((const __attribute__((address_space(1))) void*)g,
                                   (__attribute__((address_space(3))) void*)l,
                                   16, 0, 0);
}

// ---------------------------------------------------------------- fp32 -> bf16 convert
__global__ __launch_bounds__(256) void k_cvt(const float* __restrict__ in,
                                             bf16_t* __restrict__ out, int n8) {
  for (int i = blockIdx.x * blockDim.x + threadIdx.x; i < n8;
       i += gridDim.x * blockDim.x) {
    const float4* p = (const float4*)(in + (size_t)i * 8);
    float4 a = p[0], b = p[1];
    bf16x8 o;
    o[0] = (bf16_t)a.x; o[1] = (bf16_t)a.y; o[2] = (bf16_t)a.z; o[3] = (bf16_t)a.w;
    o[4] = (bf16_t)b.x; o[5] = (bf16_t)b.y; o[6] = (bf16_t)b.z; o[7] = (bf16_t)b.w;
    *(bf16x8*)(out + (size_t)i * 8) = o;
  }
}

// ---------------------------------------------------------------- pack Wq/Wk/Wv -> Wt[3][1024][1024] (B^T layout, bf16)
// Wt[z][h*64+kk][d] = W_z[h][d][kk]  (Wq scaled by 1/sqrt(DH)=0.125)
__global__ __launch_bounds__(256) void k_pack(const float* __restrict__ Wq,
                                              const float* __restrict__ Wk,
                                              const float* __restrict__ Wv,
                                              bf16_t* __restrict__ Wt) {
  const int z = blockIdx.z;
  const float* W = (z == 0) ? Wq : ((z == 1) ? Wk : Wv);
  const float scale = (z == 0) ? 0.125f : 1.0f;
  const int h  = blockIdx.y;
  const int d0 = blockIdx.x * 64;

  __shared__ float tile[64][65];   // [d_local][kk]
  const int t  = threadIdx.x;
  const int r  = t >> 2;           // 0..63
  const int c0 = (t & 3) * 16;     // 0,16,32,48

  const float* src = W + ((size_t)h * D_ + d0 + r) * DH_ + c0;
#pragma unroll
  for (int j4 = 0; j4 < 4; ++j4) {
    float4 v = *(const float4*)(src + j4 * 4);
    tile[r][c0 + j4 * 4 + 0] = v.x;
    tile[r][c0 + j4 * 4 + 1] = v.y;
    tile[r][c0 + j4 * 4 + 2] = v.z;
    tile[r][c0 + j4 * 4 + 3] = v.w;
  }
  __syncthreads();

  const int kk = r, dd0 = c0;
  bf16_t* dst = Wt + ((size_t)z * D_ + h * DH_ + kk) * D_ + d0 + dd0;
  bf16x8 o0, o1;
#pragma unroll
  for (int j = 0; j < 8; ++j) {
    o0[j] = (bf16_t)(tile[dd0 + j][kk] * scale);
    o1[j] = (bf16_t)(tile[dd0 + 8 + j][kk] * scale);
  }
  *(bf16x8*)(dst)     = o0;
  *(bf16x8*)(dst + 8) = o1;
}

// ---------------------------------------------------------------- GEMM  C[M,N] = A[M,K] * B[N,K]^T
// m97 structure: 128x128 tile, BK=32, 4 waves (2x2), 4x4 16x16x32 frags/wave.
// MODE 0: z-indexed (3 projections), bf16 out.  MODE 1: fp32 out + bias.
template <int MODE>
__global__ __launch_bounds__(256) void k_gemm(
    const bf16_t* __restrict__ A0, const bf16_t* __restrict__ A1,
    const bf16_t* __restrict__ A2, const bf16_t* __restrict__ W,
    bf16_t* __restrict__ O0, bf16_t* __restrict__ O1, bf16_t* __restrict__ O2,
    float* __restrict__ OF, const float* __restrict__ bias,
    int M, int N, int K) {
  const int z = blockIdx.z;
  const bf16_t* A  = (MODE == 0) ? (z == 0 ? A0 : (z == 1 ? A1 : A2)) : A0;
  const bf16_t* Bt = (MODE == 0) ? (W + (size_t)z * N * K) : W;
  bf16_t* OB = (MODE == 0) ? (z == 0 ? O0 : (z == 1 ? O1 : O2)) : nullptr;

  __shared__ bf16_t As[128 * 32];
  __shared__ bf16_t Bs[128 * 32];

  const int tid  = threadIdx.x;
  const int w    = tid >> 6, lane = tid & 63;
  const int wm   = w >> 1,   wn   = w & 1;
  const int g    = lane >> 4, cl  = lane & 15;
  const int m0   = blockIdx.x * 128, n0 = blockIdx.y * 128;
  const int r_a  = lane >> 2;            // row within chunk-group
  const int c_a  = (lane & 3) * 8;       // col (elements)

  f32x4 acc[4][4] = {};

  for (int k0 = 0; k0 < K; k0 += 32) {
#pragma unroll
    for (int it = 0; it < 2; ++it) {
      const int c16 = it * 4 + w;                 // wave-uniform chunk id
      const int row = c16 * 16 + r_a;
      gload_lds16(A  + (size_t)(m0 + row) * K + (k0 + c_a),
                  (bf16_t*)((char*)As + c16 * 1024));
      gload_lds16(Bt + (size_t)(n0 + row) * K + (k0 + c_a),
                  (bf16_t*)((char*)Bs + c16 * 1024));
    }
    __syncthreads();

    bf16x8 af[4], bfv[4];
#pragma unroll
    for (int mi = 0; mi < 4; ++mi)
      af[mi] = *(const bf16x8*)&As[(wm * 64 + mi * 16 + cl) * 32 + g * 8];
#pragma unroll
    for (int ni = 0; ni < 4; ++ni)
      bfv[ni] = *(const bf16x8*)&Bs[(wn * 64 + ni * 16 + cl) * 32 + g * 8];
#pragma unroll
    for (int mi = 0; mi < 4; ++mi)
#pragma unroll
      for (int ni = 0; ni < 4; ++ni)
        acc[mi][ni] = __builtin_amdgcn_mfma_f32_16x16x32_bf16(
            af[mi], bfv[ni], acc[mi][ni], 0, 0, 0);
    __syncthreads();
  }

  // epilogue: C/D layout col = lane&15, row = (lane>>4)*4 + i  [m89-verified]
#pragma unroll
  for (int mi = 0; mi < 4; ++mi) {
#pragma unroll
    for (int ni = 0; ni < 4; ++ni) {
      const int col = n0 + wn * 64 + ni * 16 + cl;
#pragma unroll
      for (int i = 0; i < 4; ++i) {
        const int row = m0 + wm * 64 + mi * 16 + g * 4 + i;
        if (MODE == 0)
          OB[(size_t)row * N + col] = (bf16_t)acc[mi][ni][i];
        else
          OF[(size_t)row * N + col] = acc[mi][ni][i] + bias[col];
      }
    }
  }
}

// ---------------------------------------------------------------- causal flash attention
// grid (S/64, B*H), 256 threads = 4 waves; wave w owns q rows [q0+16w, q0+16w+16)
// KV tiles of 64. Scale 1/sqrt(DH) pre-folded into Wq.
__global__ __launch_bounds__(256) void k_attn(const bf16_t* __restrict__ Qp,
                                              const bf16_t* __restrict__ Kp,
                                              const bf16_t* __restrict__ Vp,
                                              bf16_t* __restrict__ AO,
                                              const int* __restrict__ causal_p) {
  __shared__ bf16_t Ks[64 * 72];     // K tile row-major [kv][d], pad 8 -> conflict-free b128
  __shared__ bf16_t Vs[64 * 64];     // V tile linear (gload_lds dest)
  __shared__ bf16_t Vt[64 * 72];     // V^T tile [d][kv], pad 8
  __shared__ bf16_t Pb[4][16 * 72];  // per-wave P [q_local][kv], pad 8

  const int tid  = threadIdx.x;
  const int w    = tid >> 6, lane = tid & 63;
  const int g    = lane >> 4, cl  = lane & 15;
  const int bh   = blockIdx.y;
  const int b    = bh >> 4, h = bh & 15;
  const int qb   = gridDim.x - 1 - blockIdx.x;   // long blocks launch first
  const int q0   = qb * 64;
  const int causal = *causal_p;
  const int nt   = causal ? (qb + 1) : (S_ >> 6);

  const size_t base = ((size_t)b * S_) * D_ + (size_t)h * DH_;

  // Q fragments held in registers for the whole block
  bf16x8 aq[2];
#pragma unroll
  for (int ks = 0; ks < 2; ++ks)
    aq[ks] = *(const bf16x8*)(Qp + base + (size_t)(q0 + w * 16 + cl) * D_ +
                              ks * 32 + g * 8);

  f32x4 acc_o[4] = {};
  float m_run[4], l_run[4];
#pragma unroll
  for (int i = 0; i < 4; ++i) { m_run[i] = -1e30f; l_run[i] = 0.f; }

  const int kr  = tid >> 3;          // K stage row (0..31, +32 2nd pass)
  const int kc  = (tid & 7) * 8;     // K stage col
  const int vd  = tid & 63;          // V transpose: d
  const int vk0 = (tid >> 6) * 16;   // V transpose: kv base

  for (int t = 0; t < nt; ++t) {
    const int kv0 = t * 64;

    // ---- stage K (reg->LDS, padded) and V (gload_lds, linear) ----
#pragma unroll
    for (int p = 0; p < 2; ++p) {
      bf16x8 kvv = *(const bf16x8*)(Kp + base + (size_t)(kv0 + p * 32 + kr) * D_ + kc);
      *(bf16x8*)&Ks[(p * 32 + kr) * 72 + kc] = kvv;
    }
#pragma unroll
    for (int it = 0; it < 2; ++it) {
      const int c16 = it * 4 + w;
      const int row = c16 * 8 + (lane >> 3);
      const int col = (lane & 7) * 8;
      gload_lds16(Vp + base + (size_t)(kv0 + row) * D_ + col,
                  (bf16_t*)((char*)Vs + c16 * 1024));
    }
    __syncthreads();

    // ---- transpose Vs -> Vt (column reads 2-way, b128 writes conflict-free) ----
    {
      bf16x8 w0, w1;
#pragma unroll
      for (int j = 0; j < 8; ++j) {
        w0[j] = Vs[(vk0 + j) * 64 + vd];
        w1[j] = Vs[(vk0 + 8 + j) * 64 + vd];
      }
      *(bf16x8*)&Vt[vd * 72 + vk0]     = w0;
      *(bf16x8*)&Vt[vd * 72 + vk0 + 8] = w1;
    }

    // ---- QK^T: S[16 q][64 kv] per wave ----
    f32x4 sc[4];
    const f32x4 zero4 = {0.f, 0.f, 0.f, 0.f};
#pragma unroll
    for (int c = 0; c < 4; ++c) {
      sc[c] = zero4;
#pragma unroll
      for (int ks = 0; ks < 2; ++ks) {
        bf16x8 kf = *(const bf16x8*)&Ks[(c * 16 + cl) * 72 + ks * 32 + g * 8];
        sc[c] = __builtin_amdgcn_mfma_f32_16x16x32_bf16(aq[ks], kf, sc[c], 0, 0, 0);
      }
    }

    // ---- causal mask (only diagonal tile can cross) ----
    if (causal && t == nt - 1) {
#pragma unroll
      for (int c = 0; c < 4; ++c)
#pragma unroll
        for (int i = 0; i < 4; ++i) {
          const int qg = q0 + w * 16 + g * 4 + i;
          const int kg = kv0 + c * 16 + cl;
          if (kg > qg) sc[c][i] = -1e30f;
        }
    }

    // ---- online softmax (row reduce over 16-lane group) ----
    float mx[4], alpha[4];
#pragma unroll
    for (int i = 0; i < 4; ++i) {
      float m1 = fmaxf(fmaxf(sc[0][i], sc[1][i]), fmaxf(sc[2][i], sc[3][i]));
      m1 = fmaxf(m1, __shfl_xor(m1, 1));
      m1 = fmaxf(m1, __shfl_xor(m1, 2));
      m1 = fmaxf(m1, __shfl_xor(m1, 4));
      m1 = fmaxf(m1, __shfl_xor(m1, 8));
      const float mnew = fmaxf(m_run[i], m1);
      alpha[i] = exp2f((m_run[i] - mnew) * 1.44269504f);
      m_run[i] = mnew;
      mx[i] = mnew;
    }
#pragma unroll
    for (int c = 0; c < 4; ++c)
#pragma unroll
      for (int i = 0; i < 4; ++i)
        sc[c][i] = exp2f((sc[c][i] - mx[i]) * 1.44269504f);
#pragma unroll
    for (int i = 0; i < 4; ++i) {
      float s = sc[0][i] + sc[1][i] + sc[2][i] + sc[3][i];
      s += __shfl_xor(s, 1);
      s += __shfl_xor(s, 2);
      s += __shfl_xor(s, 4);
      s += __shfl_xor(s, 8);
      l_run[i] = l_run[i] * alpha[i] + s;
      acc_o[0][i] *= alpha[i];
      acc_o[1][i] *= alpha[i];
      acc_o[2][i] *= alpha[i];
      acc_o[3][i] *= alpha[i];
    }

    // ---- P -> LDS (bf16, per-wave buffer) ----
#pragma unroll
    for (int c = 0; c < 4; ++c)
#pragma unroll
      for (int i = 0; i < 4; ++i)
        Pb[w][(g * 4 + i) * 72 + c * 16 + cl] = (bf16_t)sc[c][i];

    __syncthreads();   // Vt ready (and P ordering within wave)

    // ---- PV: O[16 q][64 d] += P[16][64] * V[64][64] ----
#pragma unroll
    for (int ks = 0; ks < 2; ++ks) {
      bf16x8 pa = *(const bf16x8*)&Pb[w][cl * 72 + ks * 32 + g * 8];
#pragma unroll
      for (int dg = 0; dg < 4; ++dg) {
        bf16x8 vf = *(const bf16x8*)&Vt[(dg * 16 + cl) * 72 + ks * 32 + g * 8];
        acc_o[dg] = __builtin_amdgcn_mfma_f32_16x16x32_bf16(pa, vf, acc_o[dg], 0, 0, 0);
      }
    }
    __syncthreads();   // protect Ks/Vs/Vt before next stage
  }

  // ---- normalize + write AO[b, q, h*64 + d] (bf16) ----
#pragma unroll
  for (int dg = 0; dg < 4; ++dg)
#pragma unroll
    for (int i = 0; i < 4; ++i) {
      const int q = q0 + w * 16 + g * 4 + i;
      AO[base + (size_t)q * D_ + dg * 16 + cl] = (bf16_t)(acc_o[dg][i] / l_run[i]);
    }
}

// ---------------------------------------------------------------- launch
extern "C" void kernel_launch(void* const* d_in, const int* in_sizes, int n_in,
                              void* d_out, int out_size, void* d_ws, size_t ws_size,
                              hipStream_t stream) {
  const float* query = (const float*)d_in[0];
  const float* key_  = (const float*)d_in[1];
  const float* value = (const float*)d_in[2];
  const float* Wq    = (const float*)d_in[3];
  const float* Wk    = (const float*)d_in[4];
  const float* Wv    = (const float*)d_in[5];
  const float* Wo    = (const float*)d_in[6];
  const float* bo    = (const float*)d_in[7];
  const int*   causal = (const int*)d_in[8];
  float* out = (float*)d_out;

  char* ws = (char*)d_ws;
  size_t off = 0;
  auto alloc = [&](size_t bytes) {
    char* p = ws + off;
    off += (bytes + 255) & ~(size_t)255;
    return p;
  };
  const size_t TB = (size_t)MTOT * D_ * sizeof(bf16_t);   // 16 MiB
  bf16_t* qin = (bf16_t*)alloc(TB);    // reused as AO after projections
  bf16_t* kin = (bf16_t*)alloc(TB);
  bf16_t* vin = (bf16_t*)alloc(TB);
  bf16_t* Qp  = (bf16_t*)alloc(TB);
  bf16_t* Kp  = (bf16_t*)alloc(TB);
  bf16_t* Vp  = (bf16_t*)alloc(TB);
  bf16_t* wt  = (bf16_t*)alloc((size_t)3 * D_ * D_ * sizeof(bf16_t));
  bf16_t* wob = (bf16_t*)alloc((size_t)D_ * D_ * sizeof(bf16_t));
  bf16_t* ao  = qin;   // qin dead after projection GEMM

  const int n8 = MTOT * D_ / 8;
  k_cvt<<<2048, 256, 0, stream>>>(query, qin, n8);
  k_cvt<<<2048, 256, 0, stream>>>(key_,  kin, n8);
  k_cvt<<<2048, 256, 0, stream>>>(value, vin, n8);
  k_cvt<<<512, 256, 0, stream>>>(Wo, wob, D_ * D_ / 8);
  k_pack<<<dim3(16, 16, 3), 256, 0, stream>>>(Wq, Wk, Wv, wt);

  k_gemm<0><<<dim3(MTOT / 128, D_ / 128, 3), 256, 0, stream>>>(
      qin, kin, vin, wt, Qp, Kp, Vp, nullptr, nullptr, MTOT, D_, D_);

  k_attn<<<dim3(S_ / 64, B_ * H_), 256, 0, stream>>>(Qp, Kp, Vp, ao, causal);

  k_gemm<1><<<dim3(MTOT / 128, D_ / 128, 1), 256, 0, stream>>>(
      ao, nullptr, nullptr, wob, nullptr, nullptr, nullptr, out, bo, MTOT, D_, D_);
}

// Round 7
// 472.222 us; speedup vs baseline: 1.1197x; 1.1197x over previous
//
#include <hip/hip_runtime.h>
#include <hip/hip_bf16.h>
#include <stdint.h>

typedef __bf16 bf16_t;
typedef __bf16 bf16x8 __attribute__((ext_vector_type(8)));
typedef float  f32x4  __attribute__((ext_vector_type(4)));

#define B_   4
#define S_   2048
#define D_   1024
#define H_   16
#define DH_  64
#define MTOT (B_ * S_)   // 8192

// ---------------------------------------------------------------- utilities
__device__ __forceinline__ void gload_lds16(const void* g, void* l) {
  // direct global->LDS, 16B per lane; LDS dest = wave-uniform base + lane*16
  __builtin_amdgcn_global_load_lds((const __attribute__((address_space(1))) void*)g,
                                   (__attribute__((address_space(3))) void*)l,
                                   16, 0, 0);
}

// ---------------------------------------------------------------- fp32 -> bf16 convert
__global__ __launch_bounds__(256) void k_cvt(const float* __restrict__ in,
                                             bf16_t* __restrict__ out, int n8) {
  for (int i = blockIdx.x * blockDim.x + threadIdx.x; i < n8;
       i += gridDim.x * blockDim.x) {
    const float4* p = (const float4*)(in + (size_t)i * 8);
    float4 a = p[0], b = p[1];
    bf16x8 o;
    o[0] = (bf16_t)a.x; o[1] = (bf16_t)a.y; o[2] = (bf16_t)a.z; o[3] = (bf16_t)a.w;
    o[4] = (bf16_t)b.x; o[5] = (bf16_t)b.y; o[6] = (bf16_t)b.z; o[7] = (bf16_t)b.w;
    *(bf16x8*)(out + (size_t)i * 8) = o;
  }
}

// ---------------------------------------------------------------- pack Wq/Wk/Wv -> Wt[3][1024][1024] (B^T layout, bf16)
// Wt[z][h*64+kk][d] = W_z[h][d][kk]  (Wq scaled by 1/sqrt(DH)=0.125)
__global__ __launch_bounds__(256) void k_pack(const float* __restrict__ Wq,
                                              const float* __restrict__ Wk,
                                              const float* __restrict__ Wv,
                                              bf16_t* __restrict__ Wt) {
  const int z = blockIdx.z;
  const float* W = (z == 0) ? Wq : ((z == 1) ? Wk : Wv);
  const float scale = (z == 0) ? 0.125f : 1.0f;
  const int h  = blockIdx.y;
  const int d0 = blockIdx.x * 64;

  __shared__ float tile[64][65];   // [d_local][kk]
  const int t  = threadIdx.x;
  const int r  = t >> 2;           // 0..63
  const int c0 = (t & 3) * 16;     // 0,16,32,48

  const float* src = W + ((size_t)h * D_ + d0 + r) * DH_ + c0;
#pragma unroll
  for (int j4 = 0; j4 < 4; ++j4) {
    float4 v = *(const float4*)(src + j4 * 4);
    tile[r][c0 + j4 * 4 + 0] = v.x;
    tile[r][c0 + j4 * 4 + 1] = v.y;
    tile[r][c0 + j4 * 4 + 2] = v.z;
    tile[r][c0 + j4 * 4 + 3] = v.w;
  }
  __syncthreads();

  const int kk = r, dd0 = c0;
  bf16_t* dst = Wt + ((size_t)z * D_ + h * DH_ + kk) * D_ + d0 + dd0;
  bf16x8 o0, o1;
#pragma unroll
  for (int j = 0; j < 8; ++j) {
    o0[j] = (bf16_t)(tile[dd0 + j][kk] * scale);
    o1[j] = (bf16_t)(tile[dd0 + 8 + j][kk] * scale);
  }
  *(bf16x8*)(dst)     = o0;
  *(bf16x8*)(dst + 8) = o1;
}

// ---------------------------------------------------------------- GEMM  C[M,N] = A[M,K] * B[N,K]^T
// m97 structure: 128x128 tile, BK=32, 4 waves (2x2), 4x4 16x16x32 frags/wave.
// MODE 0: z-indexed (3 projections), bf16 out.  MODE 1: fp32 out + bias.
template <int MODE>
__global__ __launch_bounds__(256) void k_gemm(
    const bf16_t* __restrict__ A0, const bf16_t* __restrict__ A1,
    const bf16_t* __restrict__ A2, const bf16_t* __restrict__ W,
    bf16_t* __restrict__ O0, bf16_t* __restrict__ O1, bf16_t* __restrict__ O2,
    float* __restrict__ OF, const float* __restrict__ bias,
    int M, int N, int K) {
  const int z = blockIdx.z;
  const bf16_t* A  = (MODE == 0) ? (z == 0 ? A0 : (z == 1 ? A1 : A2)) : A0;
  const bf16_t* Bt = (MODE == 0) ? (W + (size_t)z * N * K) : W;
  bf16_t* OB = (MODE == 0) ? (z == 0 ? O0 : (z == 1 ? O1 : O2)) : nullptr;

  __shared__ bf16_t As[128 * 32];
  __shared__ bf16_t Bs[128 * 32];

  const int tid  = threadIdx.x;
  const int w    = tid >> 6, lane = tid & 63;
  const int wm   = w >> 1,   wn   = w & 1;
  const int g    = lane >> 4, cl  = lane & 15;
  const int m0   = blockIdx.x * 128, n0 = blockIdx.y * 128;
  const int r_a  = lane >> 2;            // row within chunk-group
  const int c_a  = (lane & 3) * 8;       // col (elements)

  f32x4 acc[4][4] = {};

  for (int k0 = 0; k0 < K; k0 += 32) {
#pragma unroll
    for (int it = 0; it < 2; ++it) {
      const int c16 = it * 4 + w;                 // wave-uniform chunk id
      const int row = c16 * 16 + r_a;
      gload_lds16(A  + (size_t)(m0 + row) * K + (k0 + c_a),
                  (bf16_t*)((char*)As + c16 * 1024));
      gload_lds16(Bt + (size_t)(n0 + row) * K + (k0 + c_a),
                  (bf16_t*)((char*)Bs + c16 * 1024));
    }
    __syncthreads();

    bf16x8 af[4], bfv[4];
#pragma unroll
    for (int mi = 0; mi < 4; ++mi)
      af[mi] = *(const bf16x8*)&As[(wm * 64 + mi * 16 + cl) * 32 + g * 8];
#pragma unroll
    for (int ni = 0; ni < 4; ++ni)
      bfv[ni] = *(const bf16x8*)&Bs[(wn * 64 + ni * 16 + cl) * 32 + g * 8];
#pragma unroll
    for (int mi = 0; mi < 4; ++mi)
#pragma unroll
      for (int ni = 0; ni < 4; ++ni)
        acc[mi][ni] = __builtin_amdgcn_mfma_f32_16x16x32_bf16(
            af[mi], bfv[ni], acc[mi][ni], 0, 0, 0);
    __syncthreads();
  }

  // epilogue: C/D layout col = lane&15, row = (lane>>4)*4 + i  [m89-verified]
#pragma unroll
  for (int mi = 0; mi < 4; ++mi) {
#pragma unroll
    for (int ni = 0; ni < 4; ++ni) {
      const int col = n0 + wn * 64 + ni * 16 + cl;
#pragma unroll
      for (int i = 0; i < 4; ++i) {
        const int row = m0 + wm * 64 + mi * 16 + g * 4 + i;
        if (MODE == 0)
          OB[(size_t)row * N + col] = (bf16_t)acc[mi][ni][i];
        else
          OF[(size_t)row * N + col] = acc[mi][ni][i] + bias[col];
      }
    }
  }
}

// ---------------------------------------------------------------- causal flash attention (v2)
// grid (S/128, B*H), 256 threads = 4 waves; wave w owns q rows [q0+32w, q0+32w+32)
// KV tiles of 64, single-buffered K (async reg split), double-buffered V (gload_lds).
// Scale 1/sqrt(DH) pre-folded into Wq.
__global__ __launch_bounds__(256, 3) void k_attn(const bf16_t* __restrict__ Qp,
                                                 const bf16_t* __restrict__ Kp,
                                                 const bf16_t* __restrict__ Vp,
                                                 bf16_t* __restrict__ AO,
                                                 const int* __restrict__ causal_p) {
  __shared__ bf16_t Ks[64 * 72];       // K tile [kv][d], pad 8 (single buffer, async-split staging)
  __shared__ bf16_t Vs[2 * 64 * 64];   // V tile linear, double-buffered (gload_lds dest)
  __shared__ bf16_t Vt[64 * 72];       // V^T tile [d][kv], pad 8 (rebuilt per tile)
  __shared__ bf16_t Pb[4][32 * 72];    // per-wave P [q_local 32][kv 64], pad 8

  const int tid  = threadIdx.x;
  const int w    = tid >> 6, lane = tid & 63;
  const int g    = lane >> 4, cl  = lane & 15;
  const int bh   = blockIdx.y;
  const int b    = bh >> 4, h = bh & 15;
  const int qb   = gridDim.x - 1 - blockIdx.x;   // long blocks launch first
  const int q0   = qb * 128;
  const int causal = *causal_p;
  const int nt   = causal ? (2 * qb + 2) : (S_ >> 6);
  const int base_q = q0 + w * 32;

  const size_t base = ((size_t)b * S_) * D_ + (size_t)h * DH_;

  // Q fragments held in registers for the whole block
  bf16x8 aq[2][2];
#pragma unroll
  for (int qi = 0; qi < 2; ++qi)
#pragma unroll
    for (int ks = 0; ks < 2; ++ks)
      aq[qi][ks] = *(const bf16x8*)(Qp + base + (size_t)(base_q + qi * 16 + cl) * D_ +
                                    ks * 32 + g * 8);

  f32x4 acc_o[2][4] = {};
  float m_run[2][4], l_run[2][4];
#pragma unroll
  for (int qi = 0; qi < 2; ++qi)
#pragma unroll
    for (int i = 0; i < 4; ++i) { m_run[qi][i] = -1e30f; l_run[qi][i] = 0.f; }

  bf16x8 ones;
#pragma unroll
  for (int j = 0; j < 8; ++j) ones[j] = (bf16_t)1.0f;

  const int kr  = tid >> 3;          // K stage row (0..31, +32 2nd chunk)
  const int kc  = (tid & 7) * 8;     // K stage col
  const int vd  = tid & 63;          // V transpose: d
  const int vk0 = w * 16;            // V transpose: kv base

  // ---- prologue: stage K[0] (reg->LDS) and V[0] (gload_lds, Vs buf 0) ----
  bf16x8 kreg[2];
  kreg[0] = *(const bf16x8*)(Kp + base + (size_t)(kr) * D_ + kc);
  kreg[1] = *(const bf16x8*)(Kp + base + (size_t)(32 + kr) * D_ + kc);
#pragma unroll
  for (int it = 0; it < 2; ++it) {
    const int c16 = it * 4 + w;
    gload_lds16(Vp + base + (size_t)(c16 * 8 + (lane >> 3)) * D_ + (lane & 7) * 8,
                (char*)Vs + c16 * 1024);
  }
  *(bf16x8*)&Ks[(kr) * 72 + kc]      = kreg[0];
  *(bf16x8*)&Ks[(32 + kr) * 72 + kc] = kreg[1];
  __syncthreads();

  for (int t = 0; t < nt; ++t) {
    const int kv0 = t * 64;
    const int buf = t & 1;
    const bool pf = (t + 1 < nt);

    // ---- issue prefetch for tile t+1 (K -> regs, V -> Vs[buf^1]) ----
    if (pf) {
      const int kvn = kv0 + 64;
      kreg[0] = *(const bf16x8*)(Kp + base + (size_t)(kvn + kr) * D_ + kc);
      kreg[1] = *(const bf16x8*)(Kp + base + (size_t)(kvn + 32 + kr) * D_ + kc);
#pragma unroll
      for (int it = 0; it < 2; ++it) {
        const int c16 = it * 4 + w;
        gload_lds16(Vp + base + (size_t)(kvn + c16 * 8 + (lane >> 3)) * D_ + (lane & 7) * 8,
                    (char*)Vs + (buf ^ 1) * 8192 + c16 * 1024);
      }
    }

    // ---- transpose Vs[buf] -> Vt ----
    {
      const bf16_t* vsb = Vs + buf * 4096;
      bf16x8 w0, w1;
#pragma unroll
      for (int j = 0; j < 8; ++j) {
        w0[j] = vsb[(vk0 + j) * 64 + vd];
        w1[j] = vsb[(vk0 + 8 + j) * 64 + vd];
      }
      *(bf16x8*)&Vt[vd * 72 + vk0]     = w0;
      *(bf16x8*)&Vt[vd * 72 + vk0 + 8] = w1;
    }

    const bool active    = (!causal) || (kv0 <= base_q + 31);
    const bool need_mask = causal && (kv0 + 63 > base_q);

    if (active) {
      // ---- QK^T: S[32 q][64 kv] per wave ----
      f32x4 sc[2][4];
#pragma unroll
      for (int qi = 0; qi < 2; ++qi)
#pragma unroll
        for (int c = 0; c < 4; ++c) sc[qi][c] = (f32x4){0.f, 0.f, 0.f, 0.f};

      __builtin_amdgcn_s_setprio(1);
#pragma unroll
      for (int c = 0; c < 4; ++c) {
        bf16x8 kf0 = *(const bf16x8*)&Ks[(c * 16 + cl) * 72 + g * 8];
        bf16x8 kf1 = *(const bf16x8*)&Ks[(c * 16 + cl) * 72 + 32 + g * 8];
#pragma unroll
        for (int qi = 0; qi < 2; ++qi) {
          sc[qi][c] = __builtin_amdgcn_mfma_f32_16x16x32_bf16(aq[qi][0], kf0, sc[qi][c], 0, 0, 0);
          sc[qi][c] = __builtin_amdgcn_mfma_f32_16x16x32_bf16(aq[qi][1], kf1, sc[qi][c], 0, 0, 0);
        }
      }
      __builtin_amdgcn_s_setprio(0);

      // ---- causal mask ----
      if (need_mask) {
#pragma unroll
        for (int qi = 0; qi < 2; ++qi)
#pragma unroll
          for (int c = 0; c < 4; ++c)
#pragma unroll
            for (int i = 0; i < 4; ++i) {
              const int qg = base_q + qi * 16 + g * 4 + i;
              const int kg = kv0 + c * 16 + cl;
              if (kg > qg) sc[qi][c][i] = -1e30f;
            }
      }

      // ---- online softmax (max-reduce via shfl; sum deferred to ones-MFMA) ----
#pragma unroll
      for (int qi = 0; qi < 2; ++qi) {
        float alpha[4];
#pragma unroll
        for (int i = 0; i < 4; ++i) {
          float m1 = fmaxf(fmaxf(sc[qi][0][i], sc[qi][1][i]),
                           fmaxf(sc[qi][2][i], sc[qi][3][i]));
          m1 = fmaxf(m1, __shfl_xor(m1, 1));
          m1 = fmaxf(m1, __shfl_xor(m1, 2));
          m1 = fmaxf(m1, __shfl_xor(m1, 4));
          m1 = fmaxf(m1, __shfl_xor(m1, 8));
          const float mnew = fmaxf(m_run[qi][i], m1);
          alpha[i] = exp2f((m_run[qi][i] - mnew) * 1.44269504f);
          m_run[qi][i] = mnew;
        }
#pragma unroll
        for (int i = 0; i < 4; ++i) {
          l_run[qi][i] *= alpha[i];
          acc_o[qi][0][i] *= alpha[i];
          acc_o[qi][1][i] *= alpha[i];
          acc_o[qi][2][i] *= alpha[i];
          acc_o[qi][3][i] *= alpha[i];
        }
        // P = exp(S - m), bf16, to per-wave LDS buffer
#pragma unroll
        for (int c = 0; c < 4; ++c)
#pragma unroll
          for (int i = 0; i < 4; ++i) {
            const float p = exp2f((sc[qi][c][i] - m_run[qi][i]) * 1.44269504f);
            Pb[w][(qi * 16 + g * 4 + i) * 72 + c * 16 + cl] = (bf16_t)p;
          }
      }
    }

    __syncthreads();   // Vt + Pb ready; all QK reads of Ks complete

    // ---- write prefetched K[t+1] into Ks (consumed next iter) ----
    if (pf) {
      *(bf16x8*)&Ks[(kr) * 72 + kc]      = kreg[0];
      *(bf16x8*)&Ks[(32 + kr) * 72 + kc] = kreg[1];
    }

    if (active) {
      // ---- PV: O[32 q][64 d] += P * V ; row-sums via ones-MFMA ----
      f32x4 sacc[2] = {};
      __builtin_amdgcn_s_setprio(1);
#pragma unroll
      for (int ks = 0; ks < 2; ++ks) {
        bf16x8 pa0 = *(const bf16x8*)&Pb[w][(cl) * 72 + ks * 32 + g * 8];
        bf16x8 pa1 = *(const bf16x8*)&Pb[w][(16 + cl) * 72 + ks * 32 + g * 8];
        sacc[0] = __builtin_amdgcn_mfma_f32_16x16x32_bf16(pa0, ones, sacc[0], 0, 0, 0);
        sacc[1] = __builtin_amdgcn_mfma_f32_16x16x32_bf16(pa1, ones, sacc[1], 0, 0, 0);
#pragma unroll
        for (int dg = 0; dg < 4; ++dg) {
          bf16x8 vf = *(const bf16x8*)&Vt[(dg * 16 + cl) * 72 + ks * 32 + g * 8];
          acc_o[0][dg] = __builtin_amdgcn_mfma_f32_16x16x32_bf16(pa0, vf, acc_o[0][dg], 0, 0, 0);
          acc_o[1][dg] = __builtin_amdgcn_mfma_f32_16x16x32_bf16(pa1, vf, acc_o[1][dg], 0, 0, 0);
        }
      }
      __builtin_amdgcn_s_setprio(0);
#pragma unroll
      for (int qi = 0; qi < 2; ++qi)
#pragma unroll
        for (int i = 0; i < 4; ++i) l_run[qi][i] += sacc[qi][i];
    }

    __syncthreads();   // PV done; Ks[t+1] visible; Vs[buf^1] gload drained
  }

  // ---- normalize + write AO[b, q, h*64 + d] (bf16) ----
#pragma unroll
  for (int qi = 0; qi < 2; ++qi)
#pragma unroll
    for (int dg = 0; dg < 4; ++dg)
#pragma unroll
      for (int i = 0; i < 4; ++i) {
        const int q = base_q + qi * 16 + g * 4 + i;
        AO[base + (size_t)q * D_ + dg * 16 + cl] = (bf16_t)(acc_o[qi][dg][i] / l_run[qi][i]);
      }
}

// ---------------------------------------------------------------- launch
extern "C" void kernel_launch(void* const* d_in, const int* in_sizes, int n_in,
                              void* d_out, int out_size, void* d_ws, size_t ws_size,
                              hipStream_t stream) {
  const float* query = (const float*)d_in[0];
  const float* key_  = (const float*)d_in[1];
  const float* value = (const float*)d_in[2];
  const float* Wq    = (const float*)d_in[3];
  const float* Wk    = (const float*)d_in[4];
  const float* Wv    = (const float*)d_in[5];
  const float* Wo    = (const float*)d_in[6];
  const float* bo    = (const float*)d_in[7];
  const int*   causal = (const int*)d_in[8];
  float* out = (float*)d_out;

  char* ws = (char*)d_ws;
  size_t off = 0;
  auto alloc = [&](size_t bytes) {
    char* p = ws + off;
    off += (bytes + 255) & ~(size_t)255;
    return p;
  };
  const size_t TB = (size_t)MTOT * D_ * sizeof(bf16_t);   // 16 MiB
  bf16_t* qin = (bf16_t*)alloc(TB);    // reused as AO after projections
  bf16_t* kin = (bf16_t*)alloc(TB);
  bf16_t* vin = (bf16_t*)alloc(TB);
  bf16_t* Qp  = (bf16_t*)alloc(TB);
  bf16_t* Kp  = (bf16_t*)alloc(TB);
  bf16_t* Vp  = (bf16_t*)alloc(TB);
  bf16_t* wt  = (bf16_t*)alloc((size_t)3 * D_ * D_ * sizeof(bf16_t));
  bf16_t* wob = (bf16_t*)alloc((size_t)D_ * D_ * sizeof(bf16_t));
  bf16_t* ao  = qin;   // qin dead after projection GEMM

  const int n8 = MTOT * D_ / 8;
  k_cvt<<<2048, 256, 0, stream>>>(query, qin, n8);
  k_cvt<<<2048, 256, 0, stream>>>(key_,  kin, n8);
  k_cvt<<<2048, 256, 0, stream>>>(value, vin, n8);
  k_cvt<<<512, 256, 0, stream>>>(Wo, wob, D_ * D_ / 8);
  k_pack<<<dim3(16, 16, 3), 256, 0, stream>>>(Wq, Wk, Wv, wt);

  k_gemm<0><<<dim3(MTOT / 128, D_ / 128, 3), 256, 0, stream>>>(
      qin, kin, vin, wt, Qp, Kp, Vp, nullptr, nullptr, MTOT, D_, D_);

  k_attn<<<dim3(S_ / 128, B_ * H_), 256, 0, stream>>>(Qp, Kp, Vp, ao, causal);

  k_gemm<1><<<dim3(MTOT / 128, D_ / 128, 1), 256, 0, stream>>>(
      ao, nullptr, nullptr, wob, nullptr, nullptr, nullptr, out, bo, MTOT, D_, D_);
}

// Round 8
// 389.163 us; speedup vs baseline: 1.3587x; 1.2134x over previous
//
#include <hip/hip_runtime.h>
#include <hip/hip_bf16.h>
#include <stdint.h>

typedef __bf16 bf16_t;
typedef __bf16 bf16x8 __attribute__((ext_vector_type(8)));
typedef float  f32x4  __attribute__((ext_vector_type(4)));

#define B_   4
#define S_   2048
#define D_   1024
#define H_   16
#define DH_  64
#define MTOT (B_ * S_)   // 8192
#define NITEMS 1024      // 16 qb x 64 bh
#define NPERS  768       // persistent blocks = 256 CU x 3

// ---------------------------------------------------------------- utilities
__device__ __forceinline__ void gload_lds16(const void* g, void* l) {
  // direct global->LDS, 16B per lane; LDS dest = wave-uniform base + lane*16
  __builtin_amdgcn_global_load_lds((const __attribute__((address_space(1))) void*)g,
                                   (__attribute__((address_space(3))) void*)l,
                                   16, 0, 0);
}

// ---------------------------------------------------------------- fp32 -> bf16 convert
__global__ __launch_bounds__(256) void k_cvt(const float* __restrict__ in,
                                             bf16_t* __restrict__ out, int n8) {
  for (int i = blockIdx.x * blockDim.x + threadIdx.x; i < n8;
       i += gridDim.x * blockDim.x) {
    const float4* p = (const float4*)(in + (size_t)i * 8);
    float4 a = p[0], b = p[1];
    bf16x8 o;
    o[0] = (bf16_t)a.x; o[1] = (bf16_t)a.y; o[2] = (bf16_t)a.z; o[3] = (bf16_t)a.w;
    o[4] = (bf16_t)b.x; o[5] = (bf16_t)b.y; o[6] = (bf16_t)b.z; o[7] = (bf16_t)b.w;
    *(bf16x8*)(out + (size_t)i * 8) = o;
  }
}

// ---------------------------------------------------------------- pack Wq/Wk/Wv -> Wt[3][1024][1024] (B^T layout, bf16)
// Wt[z][h*64+kk][d] = W_z[h][d][kk]  (Wq scaled by 1/sqrt(DH)=0.125)
__global__ __launch_bounds__(256) void k_pack(const float* __restrict__ Wq,
                                              const float* __restrict__ Wk,
                                              const float* __restrict__ Wv,
                                              bf16_t* __restrict__ Wt) {
  const int z = blockIdx.z;
  const float* W = (z == 0) ? Wq : ((z == 1) ? Wk : Wv);
  const float scale = (z == 0) ? 0.125f : 1.0f;
  const int h  = blockIdx.y;
  const int d0 = blockIdx.x * 64;

  __shared__ float tile[64][65];   // [d_local][kk]
  const int t  = threadIdx.x;
  const int r  = t >> 2;           // 0..63
  const int c0 = (t & 3) * 16;     // 0,16,32,48

  const float* src = W + ((size_t)h * D_ + d0 + r) * DH_ + c0;
#pragma unroll
  for (int j4 = 0; j4 < 4; ++j4) {
    float4 v = *(const float4*)(src + j4 * 4);
    tile[r][c0 + j4 * 4 + 0] = v.x;
    tile[r][c0 + j4 * 4 + 1] = v.y;
    tile[r][c0 + j4 * 4 + 2] = v.z;
    tile[r][c0 + j4 * 4 + 3] = v.w;
  }
  __syncthreads();

  const int kk = r, dd0 = c0;
  bf16_t* dst = Wt + ((size_t)z * D_ + h * DH_ + kk) * D_ + d0 + dd0;
  bf16x8 o0, o1;
#pragma unroll
  for (int j = 0; j < 8; ++j) {
    o0[j] = (bf16_t)(tile[dd0 + j][kk] * scale);
    o1[j] = (bf16_t)(tile[dd0 + 8 + j][kk] * scale);
  }
  *(bf16x8*)(dst)     = o0;
  *(bf16x8*)(dst + 8) = o1;
}

// ---------------------------------------------------------------- GEMM  C[M,N] = A[M,K] * B[N,K]^T
// m97 structure: 128x128 tile, BK=32, 4 waves (2x2), 4x4 16x16x32 frags/wave.
// MODE 0: z-indexed (3 projections), bf16 out.  MODE 1: fp32 out + bias.
template <int MODE>
__global__ __launch_bounds__(256) void k_gemm(
    const bf16_t* __restrict__ A0, const bf16_t* __restrict__ A1,
    const bf16_t* __restrict__ A2, const bf16_t* __restrict__ W,
    bf16_t* __restrict__ O0, bf16_t* __restrict__ O1, bf16_t* __restrict__ O2,
    float* __restrict__ OF, const float* __restrict__ bias,
    int M, int N, int K) {
  const int z = blockIdx.z;
  const bf16_t* A  = (MODE == 0) ? (z == 0 ? A0 : (z == 1 ? A1 : A2)) : A0;
  const bf16_t* Bt = (MODE == 0) ? (W + (size_t)z * N * K) : W;
  bf16_t* OB = (MODE == 0) ? (z == 0 ? O0 : (z == 1 ? O1 : O2)) : nullptr;

  __shared__ bf16_t As[128 * 32];
  __shared__ bf16_t Bs[128 * 32];

  const int tid  = threadIdx.x;
  const int w    = tid >> 6, lane = tid & 63;
  const int wm   = w >> 1,   wn   = w & 1;
  const int g    = lane >> 4, cl  = lane & 15;
  const int m0   = blockIdx.x * 128, n0 = blockIdx.y * 128;
  const int r_a  = lane >> 2;            // row within chunk-group
  const int c_a  = (lane & 3) * 8;       // col (elements)

  f32x4 acc[4][4] = {};

  for (int k0 = 0; k0 < K; k0 += 32) {
#pragma unroll
    for (int it = 0; it < 2; ++it) {
      const int c16 = it * 4 + w;                 // wave-uniform chunk id
      const int row = c16 * 16 + r_a;
      gload_lds16(A  + (size_t)(m0 + row) * K + (k0 + c_a),
                  (bf16_t*)((char*)As + c16 * 1024));
      gload_lds16(Bt + (size_t)(n0 + row) * K + (k0 + c_a),
                  (bf16_t*)((char*)Bs + c16 * 1024));
    }
    __syncthreads();

    bf16x8 af[4], bfv[4];
#pragma unroll
    for (int mi = 0; mi < 4; ++mi)
      af[mi] = *(const bf16x8*)&As[(wm * 64 + mi * 16 + cl) * 32 + g * 8];
#pragma unroll
    for (int ni = 0; ni < 4; ++ni)
      bfv[ni] = *(const bf16x8*)&Bs[(wn * 64 + ni * 16 + cl) * 32 + g * 8];
#pragma unroll
    for (int mi = 0; mi < 4; ++mi)
#pragma unroll
      for (int ni = 0; ni < 4; ++ni)
        acc[mi][ni] = __builtin_amdgcn_mfma_f32_16x16x32_bf16(
            af[mi], bfv[ni], acc[mi][ni], 0, 0, 0);
    __syncthreads();
  }

  // epilogue: C/D layout col = lane&15, row = (lane>>4)*4 + i  [m89-verified]
#pragma unroll
  for (int mi = 0; mi < 4; ++mi) {
#pragma unroll
    for (int ni = 0; ni < 4; ++ni) {
      const int col = n0 + wn * 64 + ni * 16 + cl;
#pragma unroll
      for (int i = 0; i < 4; ++i) {
        const int row = m0 + wm * 64 + mi * 16 + g * 4 + i;
        if (MODE == 0)
          OB[(size_t)row * N + col] = (bf16_t)acc[mi][ni][i];
        else
          OF[(size_t)row * N + col] = acc[mi][ni][i] + bias[col];
      }
    }
  }
}

// ---------------------------------------------------------------- causal flash attention (v3: persistent work-queue)
// grid = NPERS blocks x 256 threads (4 waves); items = (qb, bh), longest-first.
// Per item: wave w owns q rows [qb*128+32w, +32). KV tiles of 64.
// Inner tile loop identical to v2 (K reg-prefetch, V gload_lds dbuf, ones-MFMA sums).
__global__ __launch_bounds__(256, 3) void k_attn(const bf16_t* __restrict__ Qp,
                                                 const bf16_t* __restrict__ Kp,
                                                 const bf16_t* __restrict__ Vp,
                                                 bf16_t* __restrict__ AO,
                                                 int* __restrict__ wq_ctr,
                                                 const int* __restrict__ causal_p) {
  __shared__ bf16_t Ks[64 * 72];       // K tile [kv][d], pad 8 (single buffer, async-split staging)
  __shared__ bf16_t Vs[2 * 64 * 64];   // V tile linear, double-buffered (gload_lds dest)
  __shared__ bf16_t Vt[64 * 72];       // V^T tile [d][kv], pad 8 (rebuilt per tile)
  __shared__ bf16_t Pb[4][32 * 72];    // per-wave P [q_local 32][kv 64], pad 8
  __shared__ int s_item;

  const int tid  = threadIdx.x;
  const int w    = tid >> 6, lane = tid & 63;
  const int g    = lane >> 4, cl  = lane & 15;
  const int causal = *causal_p;

  bf16x8 ones;
#pragma unroll
  for (int j = 0; j < 8; ++j) ones[j] = (bf16_t)1.0f;

  const int kr  = tid >> 3;          // K stage row (0..31, +32 2nd chunk)
  const int kc  = (tid & 7) * 8;     // K stage col
  const int vd  = tid & 63;          // V transpose: d
  const int vk0 = w * 16;            // V transpose: kv base

  for (;;) {
    if (tid == 0) s_item = atomicAdd(wq_ctr, 1);
    __syncthreads();                 // publish s_item; also fences LDS from prev item
    const int item = s_item;
    if (item >= NITEMS) break;

    const int qb = 15 - (item >> 6);       // longest first
    const int bh = item & 63;
    const int b  = bh >> 4, h = bh & 15;
    const int q0 = qb * 128;
    const int nt = causal ? (2 * qb + 2) : (S_ >> 6);
    const int base_q = q0 + w * 32;
    const size_t base = ((size_t)b * S_) * D_ + (size_t)h * DH_;

    // Q fragments held in registers for the whole item
    bf16x8 aq[2][2];
#pragma unroll
    for (int qi = 0; qi < 2; ++qi)
#pragma unroll
      for (int ks = 0; ks < 2; ++ks)
        aq[qi][ks] = *(const bf16x8*)(Qp + base + (size_t)(base_q + qi * 16 + cl) * D_ +
                                      ks * 32 + g * 8);

    f32x4 acc_o[2][4] = {};
    float m_run[2][4], l_run[2][4];
#pragma unroll
    for (int qi = 0; qi < 2; ++qi)
#pragma unroll
      for (int i = 0; i < 4; ++i) { m_run[qi][i] = -1e30f; l_run[qi][i] = 0.f; }

    // ---- prologue: stage K[0] (reg->LDS) and V[0] (gload_lds, Vs buf 0) ----
    bf16x8 kreg[2];
    kreg[0] = *(const bf16x8*)(Kp + base + (size_t)(kr) * D_ + kc);
    kreg[1] = *(const bf16x8*)(Kp + base + (size_t)(32 + kr) * D_ + kc);
#pragma unroll
    for (int it = 0; it < 2; ++it) {
      const int c16 = it * 4 + w;
      gload_lds16(Vp + base + (size_t)(c16 * 8 + (lane >> 3)) * D_ + (lane & 7) * 8,
                  (char*)Vs + c16 * 1024);
    }
    *(bf16x8*)&Ks[(kr) * 72 + kc]      = kreg[0];
    *(bf16x8*)&Ks[(32 + kr) * 72 + kc] = kreg[1];
    __syncthreads();

    for (int t = 0; t < nt; ++t) {
      const int kv0 = t * 64;
      const int buf = t & 1;
      const bool pf = (t + 1 < nt);

      // ---- issue prefetch for tile t+1 (K -> regs, V -> Vs[buf^1]) ----
      if (pf) {
        const int kvn = kv0 + 64;
        kreg[0] = *(const bf16x8*)(Kp + base + (size_t)(kvn + kr) * D_ + kc);
        kreg[1] = *(const bf16x8*)(Kp + base + (size_t)(kvn + 32 + kr) * D_ + kc);
#pragma unroll
        for (int it = 0; it < 2; ++it) {
          const int c16 = it * 4 + w;
          gload_lds16(Vp + base + (size_t)(kvn + c16 * 8 + (lane >> 3)) * D_ + (lane & 7) * 8,
                      (char*)Vs + (buf ^ 1) * 8192 + c16 * 1024);
        }
      }

      // ---- transpose Vs[buf] -> Vt ----
      {
        const bf16_t* vsb = Vs + buf * 4096;
        bf16x8 w0, w1;
#pragma unroll
        for (int j = 0; j < 8; ++j) {
          w0[j] = vsb[(vk0 + j) * 64 + vd];
          w1[j] = vsb[(vk0 + 8 + j) * 64 + vd];
        }
        *(bf16x8*)&Vt[vd * 72 + vk0]     = w0;
        *(bf16x8*)&Vt[vd * 72 + vk0 + 8] = w1;
      }

      const bool active    = (!causal) || (kv0 <= base_q + 31);
      const bool need_mask = causal && (kv0 + 63 > base_q);

      if (active) {
        // ---- QK^T: S[32 q][64 kv] per wave ----
        f32x4 sc[2][4];
#pragma unroll
        for (int qi = 0; qi < 2; ++qi)
#pragma unroll
          for (int c = 0; c < 4; ++c) sc[qi][c] = (f32x4){0.f, 0.f, 0.f, 0.f};

        __builtin_amdgcn_s_setprio(1);
#pragma unroll
        for (int c = 0; c < 4; ++c) {
          bf16x8 kf0 = *(const bf16x8*)&Ks[(c * 16 + cl) * 72 + g * 8];
          bf16x8 kf1 = *(const bf16x8*)&Ks[(c * 16 + cl) * 72 + 32 + g * 8];
#pragma unroll
          for (int qi = 0; qi < 2; ++qi) {
            sc[qi][c] = __builtin_amdgcn_mfma_f32_16x16x32_bf16(aq[qi][0], kf0, sc[qi][c], 0, 0, 0);
            sc[qi][c] = __builtin_amdgcn_mfma_f32_16x16x32_bf16(aq[qi][1], kf1, sc[qi][c], 0, 0, 0);
          }
        }
        __builtin_amdgcn_s_setprio(0);

        // ---- causal mask ----
        if (need_mask) {
#pragma unroll
          for (int qi = 0; qi < 2; ++qi)
#pragma unroll
            for (int c = 0; c < 4; ++c)
#pragma unroll
              for (int i = 0; i < 4; ++i) {
                const int qg = base_q + qi * 16 + g * 4 + i;
                const int kg = kv0 + c * 16 + cl;
                if (kg > qg) sc[qi][c][i] = -1e30f;
              }
        }

        // ---- online softmax (max-reduce via shfl; sum deferred to ones-MFMA) ----
#pragma unroll
        for (int qi = 0; qi < 2; ++qi) {
          float alpha[4];
#pragma unroll
          for (int i = 0; i < 4; ++i) {
            float m1 = fmaxf(fmaxf(sc[qi][0][i], sc[qi][1][i]),
                             fmaxf(sc[qi][2][i], sc[qi][3][i]));
            m1 = fmaxf(m1, __shfl_xor(m1, 1));
            m1 = fmaxf(m1, __shfl_xor(m1, 2));
            m1 = fmaxf(m1, __shfl_xor(m1, 4));
            m1 = fmaxf(m1, __shfl_xor(m1, 8));
            const float mnew = fmaxf(m_run[qi][i], m1);
            alpha[i] = exp2f((m_run[qi][i] - mnew) * 1.44269504f);
            m_run[qi][i] = mnew;
          }
#pragma unroll
          for (int i = 0; i < 4; ++i) {
            l_run[qi][i] *= alpha[i];
            acc_o[qi][0][i] *= alpha[i];
            acc_o[qi][1][i] *= alpha[i];
            acc_o[qi][2][i] *= alpha[i];
            acc_o[qi][3][i] *= alpha[i];
          }
          // P = exp(S - m), bf16, to per-wave LDS buffer
#pragma unroll
          for (int c = 0; c < 4; ++c)
#pragma unroll
            for (int i = 0; i < 4; ++i) {
              const float p = exp2f((sc[qi][c][i] - m_run[qi][i]) * 1.44269504f);
              Pb[w][(qi * 16 + g * 4 + i) * 72 + c * 16 + cl] = (bf16_t)p;
            }
        }
      }

      __syncthreads();   // Vt + Pb ready; all QK reads of Ks complete

      // ---- write prefetched K[t+1] into Ks (consumed next iter) ----
      if (pf) {
        *(bf16x8*)&Ks[(kr) * 72 + kc]      = kreg[0];
        *(bf16x8*)&Ks[(32 + kr) * 72 + kc] = kreg[1];
      }

      if (active) {
        // ---- PV: O[32 q][64 d] += P * V ; row-sums via ones-MFMA ----
        f32x4 sacc[2] = {};
        __builtin_amdgcn_s_setprio(1);
#pragma unroll
        for (int ks = 0; ks < 2; ++ks) {
          bf16x8 pa0 = *(const bf16x8*)&Pb[w][(cl) * 72 + ks * 32 + g * 8];
          bf16x8 pa1 = *(const bf16x8*)&Pb[w][(16 + cl) * 72 + ks * 32 + g * 8];
          sacc[0] = __builtin_amdgcn_mfma_f32_16x16x32_bf16(pa0, ones, sacc[0], 0, 0, 0);
          sacc[1] = __builtin_amdgcn_mfma_f32_16x16x32_bf16(pa1, ones, sacc[1], 0, 0, 0);
#pragma unroll
          for (int dg = 0; dg < 4; ++dg) {
            bf16x8 vf = *(const bf16x8*)&Vt[(dg * 16 + cl) * 72 + ks * 32 + g * 8];
            acc_o[0][dg] = __builtin_amdgcn_mfma_f32_16x16x32_bf16(pa0, vf, acc_o[0][dg], 0, 0, 0);
            acc_o[1][dg] = __builtin_amdgcn_mfma_f32_16x16x32_bf16(pa1, vf, acc_o[1][dg], 0, 0, 0);
          }
        }
        __builtin_amdgcn_s_setprio(0);
#pragma unroll
        for (int qi = 0; qi < 2; ++qi)
#pragma unroll
          for (int i = 0; i < 4; ++i) l_run[qi][i] += sacc[qi][i];
      }

      __syncthreads();   // PV done; Ks[t+1] visible; Vs[buf^1] gload drained
    }

    // ---- normalize + write AO[b, q, h*64 + d] (bf16) ----
#pragma unroll
    for (int qi = 0; qi < 2; ++qi)
#pragma unroll
      for (int dg = 0; dg < 4; ++dg)
#pragma unroll
        for (int i = 0; i < 4; ++i) {
          const int q = base_q + qi * 16 + g * 4 + i;
          AO[base + (size_t)q * D_ + dg * 16 + cl] = (bf16_t)(acc_o[qi][dg][i] / l_run[qi][i]);
        }
  }
}

// ---------------------------------------------------------------- launch
extern "C" void kernel_launch(void* const* d_in, const int* in_sizes, int n_in,
                              void* d_out, int out_size, void* d_ws, size_t ws_size,
                              hipStream_t stream) {
  const float* query = (const float*)d_in[0];
  const float* key_  = (const float*)d_in[1];
  const float* value = (const float*)d_in[2];
  const float* Wq    = (const float*)d_in[3];
  const float* Wk    = (const float*)d_in[4];
  const float* Wv    = (const float*)d_in[5];
  const float* Wo    = (const float*)d_in[6];
  const float* bo    = (const float*)d_in[7];
  const int*   causal = (const int*)d_in[8];
  float* out = (float*)d_out;

  char* ws = (char*)d_ws;
  size_t off = 0;
  auto alloc = [&](size_t bytes) {
    char* p = ws + off;
    off += (bytes + 255) & ~(size_t)255;
    return p;
  };
  const size_t TB = (size_t)MTOT * D_ * sizeof(bf16_t);   // 16 MiB
  bf16_t* qin = (bf16_t*)alloc(TB);    // reused as AO after projections
  bf16_t* kin = (bf16_t*)alloc(TB);
  bf16_t* vin = (bf16_t*)alloc(TB);
  bf16_t* Qp  = (bf16_t*)alloc(TB);
  bf16_t* Kp  = (bf16_t*)alloc(TB);
  bf16_t* Vp  = (bf16_t*)alloc(TB);
  bf16_t* wt  = (bf16_t*)alloc((size_t)3 * D_ * D_ * sizeof(bf16_t));
  bf16_t* wob = (bf16_t*)alloc((size_t)D_ * D_ * sizeof(bf16_t));
  int*    ctr = (int*)alloc(256);
  bf16_t* ao  = qin;   // qin dead after projection GEMM

  hipMemsetAsync(ctr, 0, sizeof(int), stream);

  const int n8 = MTOT * D_ / 8;
  k_cvt<<<2048, 256, 0, stream>>>(query, qin, n8);
  k_cvt<<<2048, 256, 0, stream>>>(key_,  kin, n8);
  k_cvt<<<2048, 256, 0, stream>>>(value, vin, n8);
  k_cvt<<<512, 256, 0, stream>>>(Wo, wob, D_ * D_ / 8);
  k_pack<<<dim3(16, 16, 3), 256, 0, stream>>>(Wq, Wk, Wv, wt);

  k_gemm<0><<<dim3(MTOT / 128, D_ / 128, 3), 256, 0, stream>>>(
      qin, kin, vin, wt, Qp, Kp, Vp, nullptr, nullptr, MTOT, D_, D_);

  k_attn<<<dim3(NPERS, 1), 256, 0, stream>>>(Qp, Kp, Vp, ao, ctr, causal);

  k_gemm<1><<<dim3(MTOT / 128, D_ / 128, 1), 256, 0, stream>>>(
      ao, nullptr, nullptr, wob, nullptr, nullptr, nullptr, out, bo, MTOT, D_, D_);
}

// Round 12
// 360.592 us; speedup vs baseline: 1.4663x; 1.0792x over previous
//
#include <hip/hip_runtime.h>
#include <hip/hip_bf16.h>
#include <stdint.h>

typedef __bf16 bf16_t;
typedef __bf16 bf16x4 __attribute__((ext_vector_type(4)));
typedef __bf16 bf16x8 __attribute__((ext_vector_type(8)));
typedef float  f32x4  __attribute__((ext_vector_type(4)));

#define B_   4
#define S_   2048
#define D_   1024
#define H_   16
#define DH_  64
#define MTOT (B_ * S_)   // 8192
#define NITEMS 1024      // 16 qb x 64 bh
#define NPERS  768       // persistent blocks = 256 CU x 3

// ---------------------------------------------------------------- utilities
__device__ __forceinline__ void gload_lds16(const void* g, void* l) {
  // direct global->LDS, 16B per lane; LDS dest = wave-uniform base + lane*16
  __builtin_amdgcn_global_load_lds((const __attribute__((address_space(1))) void*)g,
                                   (__attribute__((address_space(3))) void*)l,
                                   16, 0, 0);
}

// ---------------------------------------------------------------- fp32 -> bf16 convert
__global__ __launch_bounds__(256) void k_cvt(const float* __restrict__ in,
                                             bf16_t* __restrict__ out, int n8) {
  for (int i = blockIdx.x * blockDim.x + threadIdx.x; i < n8;
       i += gridDim.x * blockDim.x) {
    const float4* p = (const float4*)(in + (size_t)i * 8);
    float4 a = p[0], b = p[1];
    bf16x8 o;
    o[0] = (bf16_t)a.x; o[1] = (bf16_t)a.y; o[2] = (bf16_t)a.z; o[3] = (bf16_t)a.w;
    o[4] = (bf16_t)b.x; o[5] = (bf16_t)b.y; o[6] = (bf16_t)b.z; o[7] = (bf16_t)b.w;
    *(bf16x8*)(out + (size_t)i * 8) = o;
  }
}

// ---------------------------------------------------------------- pack Wq/Wk/Wv -> Wt[3][1024][1024] (B^T layout, bf16)
// Wt[z][h*64+kk][d] = W_z[h][d][kk]  (Wq scaled by 1/sqrt(DH)=0.125)
__global__ __launch_bounds__(256) void k_pack(const float* __restrict__ Wq,
                                              const float* __restrict__ Wk,
                                              const float* __restrict__ Wv,
                                              bf16_t* __restrict__ Wt) {
  const int z = blockIdx.z;
  const float* W = (z == 0) ? Wq : ((z == 1) ? Wk : Wv);
  const float scale = (z == 0) ? 0.125f : 1.0f;
  const int h  = blockIdx.y;
  const int d0 = blockIdx.x * 64;

  __shared__ float tile[64][65];   // [d_local][kk]
  const int t  = threadIdx.x;
  const int r  = t >> 2;           // 0..63
  const int c0 = (t & 3) * 16;     // 0,16,32,48

  const float* src = W + ((size_t)h * D_ + d0 + r) * DH_ + c0;
#pragma unroll
  for (int j4 = 0; j4 < 4; ++j4) {
    float4 v = *(const float4*)(src + j4 * 4);
    tile[r][c0 + j4 * 4 + 0] = v.x;
    tile[r][c0 + j4 * 4 + 1] = v.y;
    tile[r][c0 + j4 * 4 + 2] = v.z;
    tile[r][c0 + j4 * 4 + 3] = v.w;
  }
  __syncthreads();

  const int kk = r, dd0 = c0;
  bf16_t* dst = Wt + ((size_t)z * D_ + h * DH_ + kk) * D_ + d0 + dd0;
  bf16x8 o0, o1;
#pragma unroll
  for (int j = 0; j < 8; ++j) {
    o0[j] = (bf16_t)(tile[dd0 + j][kk] * scale);
    o1[j] = (bf16_t)(tile[dd0 + 8 + j][kk] * scale);
  }
  *(bf16x8*)(dst)     = o0;
  *(bf16x8*)(dst + 8) = o1;
}

// ---------------------------------------------------------------- GEMM  C[M,N] = A[M,K] * B[N,K]^T
// m97 structure: 128x128 tile, BK=32, 4 waves (2x2), 4x4 16x16x32 frags/wave.
// MODE 0: z-indexed (3 projections), bf16 out.  MODE 1: fp32 out + bias.
template <int MODE>
__global__ __launch_bounds__(256) void k_gemm(
    const bf16_t* __restrict__ A0, const bf16_t* __restrict__ A1,
    const bf16_t* __restrict__ A2, const bf16_t* __restrict__ W,
    bf16_t* __restrict__ O0, bf16_t* __restrict__ O1, bf16_t* __restrict__ O2,
    float* __restrict__ OF, const float* __restrict__ bias,
    int M, int N, int K) {
  const int z = blockIdx.z;
  const bf16_t* A  = (MODE == 0) ? (z == 0 ? A0 : (z == 1 ? A1 : A2)) : A0;
  const bf16_t* Bt = (MODE == 0) ? (W + (size_t)z * N * K) : W;
  bf16_t* OB = (MODE == 0) ? (z == 0 ? O0 : (z == 1 ? O1 : O2)) : nullptr;

  __shared__ bf16_t As[128 * 32];
  __shared__ bf16_t Bs[128 * 32];

  const int tid  = threadIdx.x;
  const int w    = tid >> 6, lane = tid & 63;
  const int wm   = w >> 1,   wn   = w & 1;
  const int g    = lane >> 4, cl  = lane & 15;
  const int m0   = blockIdx.x * 128, n0 = blockIdx.y * 128;
  const int r_a  = lane >> 2;            // row within chunk-group
  const int c_a  = (lane & 3) * 8;       // col (elements)

  f32x4 acc[4][4] = {};

  for (int k0 = 0; k0 < K; k0 += 32) {
#pragma unroll
    for (int it = 0; it < 2; ++it) {
      const int c16 = it * 4 + w;                 // wave-uniform chunk id
      const int row = c16 * 16 + r_a;
      gload_lds16(A  + (size_t)(m0 + row) * K + (k0 + c_a),
                  (bf16_t*)((char*)As + c16 * 1024));
      gload_lds16(Bt + (size_t)(n0 + row) * K + (k0 + c_a),
                  (bf16_t*)((char*)Bs + c16 * 1024));
    }
    __syncthreads();

    bf16x8 af[4], bfv[4];
#pragma unroll
    for (int mi = 0; mi < 4; ++mi)
      af[mi] = *(const bf16x8*)&As[(wm * 64 + mi * 16 + cl) * 32 + g * 8];
#pragma unroll
    for (int ni = 0; ni < 4; ++ni)
      bfv[ni] = *(const bf16x8*)&Bs[(wn * 64 + ni * 16 + cl) * 32 + g * 8];
#pragma unroll
    for (int mi = 0; mi < 4; ++mi)
#pragma unroll
      for (int ni = 0; ni < 4; ++ni)
        acc[mi][ni] = __builtin_amdgcn_mfma_f32_16x16x32_bf16(
            af[mi], bfv[ni], acc[mi][ni], 0, 0, 0);
    __syncthreads();
  }

  // epilogue: C/D layout col = lane&15, row = (lane>>4)*4 + i  [m89-verified]
#pragma unroll
  for (int mi = 0; mi < 4; ++mi) {
#pragma unroll
    for (int ni = 0; ni < 4; ++ni) {
      const int col = n0 + wn * 64 + ni * 16 + cl;
#pragma unroll
      for (int i = 0; i < 4; ++i) {
        const int row = m0 + wm * 64 + mi * 16 + g * 4 + i;
        if (MODE == 0)
          OB[(size_t)row * N + col] = (bf16_t)acc[mi][ni][i];
        else
          OF[(size_t)row * N + col] = acc[mi][ni][i] + bias[col];
      }
    }
  }
}

// ---------------------------------------------------------------- causal flash attention (v4)
// Persistent work-queue (NPERS blocks), items (qb, bh) longest-first.
// Wave w owns q rows [qb*128+32w, +32). KV tiles of 64.
// v4: swapped QK^T (mfma(K,Q)) -> lane-local softmax (q=cl per lane),
//     in-lane max/sum + 2 shfl_xor, packed b64 P-writes, defer-max THR=8.
__global__ __launch_bounds__(256, 3) void k_attn(const bf16_t* __restrict__ Qp,
                                                 const bf16_t* __restrict__ Kp,
                                                 const bf16_t* __restrict__ Vp,
                                                 bf16_t* __restrict__ AO,
                                                 int* __restrict__ wq_ctr,
                                                 const int* __restrict__ causal_p) {
  __shared__ bf16_t Ks[64 * 72];       // K tile [kv][d], pad 8
  __shared__ bf16_t Vs[2 * 64 * 64];   // V tile linear, double-buffered (gload_lds dest)
  __shared__ bf16_t Vt[64 * 72];       // V^T tile [d][kv], pad 8 (rebuilt per tile)
  __shared__ bf16_t Pb[4][32 * 72];    // per-wave P [q_local 32][kv 64], pad 8
  __shared__ int s_item;

  const int tid  = threadIdx.x;
  const int w    = tid >> 6, lane = tid & 63;
  const int g    = lane >> 4, cl  = lane & 15;
  const int causal = *causal_p;
  const int gbase = (lane & 48) | ((lane & 48) >> 2);   // srcLane base: own g-group, cl=g*4

  const int kr  = tid >> 3;          // K stage row (0..31, +32 2nd chunk)
  const int kc  = (tid & 7) * 8;     // K stage col
  const int vd  = tid & 63;          // V transpose: d
  const int vk0 = w * 16;            // V transpose: kv base

  for (;;) {
    if (tid == 0) s_item = atomicAdd(wq_ctr, 1);
    __syncthreads();                 // publish s_item; also fences LDS from prev item
    const int item = s_item;
    if (item >= NITEMS) break;

    const int qb = 15 - (item >> 6);       // longest first
    const int bh = item & 63;
    const int b  = bh >> 4, h = bh & 15;
    const int q0 = qb * 128;
    const int nt = causal ? (2 * qb + 2) : (S_ >> 6);
    const int base_q = q0 + w * 32;
    const size_t base = ((size_t)b * S_) * D_ + (size_t)h * DH_;

    // Q fragments held in registers for the whole item
    bf16x8 aq[2][2];
#pragma unroll
    for (int qi = 0; qi < 2; ++qi)
#pragma unroll
      for (int ks = 0; ks < 2; ++ks)
        aq[qi][ks] = *(const bf16x8*)(Qp + base + (size_t)(base_q + qi * 16 + cl) * D_ +
                                      ks * 32 + g * 8);

    f32x4 acc_o[2][4] = {};
    float m_run[2], l_run[2];
#pragma unroll
    for (int qi = 0; qi < 2; ++qi) { m_run[qi] = -1e30f; l_run[qi] = 0.f; }

    // ---- prologue: stage K[0] (reg->LDS) and V[0] (gload_lds, Vs buf 0) ----
    bf16x8 kreg[2];
    kreg[0] = *(const bf16x8*)(Kp + base + (size_t)(kr) * D_ + kc);
    kreg[1] = *(const bf16x8*)(Kp + base + (size_t)(32 + kr) * D_ + kc);
#pragma unroll
    for (int it = 0; it < 2; ++it) {
      const int c16 = it * 4 + w;
      gload_lds16(Vp + base + (size_t)(c16 * 8 + (lane >> 3)) * D_ + (lane & 7) * 8,
                  (char*)Vs + c16 * 1024);
    }
    *(bf16x8*)&Ks[(kr) * 72 + kc]      = kreg[0];
    *(bf16x8*)&Ks[(32 + kr) * 72 + kc] = kreg[1];
    __syncthreads();

    for (int t = 0; t < nt; ++t) {
      const int kv0 = t * 64;
      const int buf = t & 1;
      const bool pf = (t + 1 < nt);

      // ---- issue prefetch for tile t+1 (K -> regs, V -> Vs[buf^1]) ----
      if (pf) {
        const int kvn = kv0 + 64;
        kreg[0] = *(const bf16x8*)(Kp + base + (size_t)(kvn + kr) * D_ + kc);
        kreg[1] = *(const bf16x8*)(Kp + base + (size_t)(kvn + 32 + kr) * D_ + kc);
#pragma unroll
        for (int it = 0; it < 2; ++it) {
          const int c16 = it * 4 + w;
          gload_lds16(Vp + base + (size_t)(kvn + c16 * 8 + (lane >> 3)) * D_ + (lane & 7) * 8,
                      (char*)Vs + (buf ^ 1) * 8192 + c16 * 1024);
        }
      }

      // ---- transpose Vs[buf] -> Vt ----
      {
        const bf16_t* vsb = Vs + buf * 4096;
        bf16x8 w0, w1;
#pragma unroll
        for (int j = 0; j < 8; ++j) {
          w0[j] = vsb[(vk0 + j) * 64 + vd];
          w1[j] = vsb[(vk0 + 8 + j) * 64 + vd];
        }
        *(bf16x8*)&Vt[vd * 72 + vk0]     = w0;
        *(bf16x8*)&Vt[vd * 72 + vk0 + 8] = w1;
      }

      const bool active    = (!causal) || (kv0 <= base_q + 31);
      const bool need_mask = causal && (kv0 + 63 > base_q);

      if (active) {
        // ---- swapped QK^T: S^T tiles; lane holds q=cl, kv=c*16+g*4+i ----
        f32x4 sc[2][4];
#pragma unroll
        for (int qi = 0; qi < 2; ++qi)
#pragma unroll
          for (int c = 0; c < 4; ++c) sc[qi][c] = (f32x4){0.f, 0.f, 0.f, 0.f};

        __builtin_amdgcn_s_setprio(1);
#pragma unroll
        for (int c = 0; c < 4; ++c) {
          bf16x8 kf0 = *(const bf16x8*)&Ks[(c * 16 + cl) * 72 + g * 8];
          bf16x8 kf1 = *(const bf16x8*)&Ks[(c * 16 + cl) * 72 + 32 + g * 8];
#pragma unroll
          for (int qi = 0; qi < 2; ++qi) {
            sc[qi][c] = __builtin_amdgcn_mfma_f32_16x16x32_bf16(kf0, aq[qi][0], sc[qi][c], 0, 0, 0);
            sc[qi][c] = __builtin_amdgcn_mfma_f32_16x16x32_bf16(kf1, aq[qi][1], sc[qi][c], 0, 0, 0);
          }
        }
        __builtin_amdgcn_s_setprio(0);

        // ---- causal mask (swapped indices: q=cl, kv=c*16+g*4+i) ----
        if (need_mask) {
#pragma unroll
          for (int qi = 0; qi < 2; ++qi) {
            const int qg = base_q + qi * 16 + cl;
#pragma unroll
            for (int c = 0; c < 4; ++c)
#pragma unroll
              for (int i = 0; i < 4; ++i) {
                const int kg = kv0 + c * 16 + g * 4 + i;
                if (kg > qg) sc[qi][c][i] = -1e30f;
              }
          }
        }

        // ---- lane-local online softmax + packed P write ----
#pragma unroll
        for (int qi = 0; qi < 2; ++qi) {
          float m4[4];
#pragma unroll
          for (int c = 0; c < 4; ++c)
            m4[c] = fmaxf(fmaxf(sc[qi][c][0], sc[qi][c][1]),
                          fmaxf(sc[qi][c][2], sc[qi][c][3]));
          float m1 = fmaxf(fmaxf(m4[0], m4[1]), fmaxf(m4[2], m4[3]));
          m1 = fmaxf(m1, __shfl_xor(m1, 16));
          m1 = fmaxf(m1, __shfl_xor(m1, 32));
          if (!__all(m1 <= m_run[qi] + 8.0f)) {      // defer-max THR=8 (T13)
            const float mnew = fmaxf(m_run[qi], m1);
            const float alpha = exp2f((m_run[qi] - mnew) * 1.44269504f);
            m_run[qi] = mnew;
            l_run[qi] *= alpha;
#pragma unroll
            for (int i = 0; i < 4; ++i) {            // broadcast alpha to O-row domain
              const float ai = __shfl(alpha, gbase + i);
              acc_o[qi][0][i] *= ai;
              acc_o[qi][1][i] *= ai;
              acc_o[qi][2][i] *= ai;
              acc_o[qi][3][i] *= ai;
            }
          }
          float s = 0.f;
#pragma unroll
          for (int c = 0; c < 4; ++c) {
            bf16x4 pv;
#pragma unroll
            for (int i = 0; i < 4; ++i) {
              const float p = exp2f((sc[qi][c][i] - m_run[qi]) * 1.44269504f);
              s += p;
              pv[i] = (bf16_t)p;
            }
            *(bf16x4*)&Pb[w][(qi * 16 + cl) * 72 + c * 16 + ((lane >> 2) & 12)] = pv;
          }
          s += __shfl_xor(s, 16);
          s += __shfl_xor(s, 32);
          l_run[qi] += s;
        }
      }

      __syncthreads();   // Vt + Pb ready; all QK reads of Ks complete

      // ---- write prefetched K[t+1] into Ks (consumed next iter) ----
      if (pf) {
        *(bf16x8*)&Ks[(kr) * 72 + kc]      = kreg[0];
        *(bf16x8*)&Ks[(32 + kr) * 72 + kc] = kreg[1];
      }

      if (active) {
        // ---- PV: O[32 q][64 d] += P * V ----
        __builtin_amdgcn_s_setprio(1);
#pragma unroll
        for (int ks = 0; ks < 2; ++ks) {
          bf16x8 pa0 = *(const bf16x8*)&Pb[w][(cl) * 72 + ks * 32 + g * 8];
          bf16x8 pa1 = *(const bf16x8*)&Pb[w][(16 + cl) * 72 + ks * 32 + g * 8];
#pragma unroll
          for (int dg = 0; dg < 4; ++dg) {
            bf16x8 vf = *(const bf16x8*)&Vt[(dg * 16 + cl) * 72 + ks * 32 + g * 8];
            acc_o[0][dg] = __builtin_amdgcn_mfma_f32_16x16x32_bf16(pa0, vf, acc_o[0][dg], 0, 0, 0);
            acc_o[1][dg] = __builtin_amdgcn_mfma_f32_16x16x32_bf16(pa1, vf, acc_o[1][dg], 0, 0, 0);
          }
        }
        __builtin_amdgcn_s_setprio(0);
      }

      __syncthreads();   // PV done; Ks[t+1] visible; Vs[buf^1] gload drained
    }

    // ---- normalize + write AO[b, q, h*64 + d] (bf16) ----
#pragma unroll
    for (int qi = 0; qi < 2; ++qi) {
      float lq[4];
#pragma unroll
      for (int i = 0; i < 4; ++i) lq[i] = __shfl(l_run[qi], gbase + i);
#pragma unroll
      for (int dg = 0; dg < 4; ++dg)
#pragma unroll
        for (int i = 0; i < 4; ++i) {
          const int q = base_q + qi * 16 + g * 4 + i;
          AO[base + (size_t)q * D_ + dg * 16 + cl] = (bf16_t)(acc_o[qi][dg][i] / lq[i]);
        }
    }
  }
}

// ---------------------------------------------------------------- launch
extern "C" void kernel_launch(void* const* d_in, const int* in_sizes, int n_in,
                              void* d_out, int out_size, void* d_ws, size_t ws_size,
                              hipStream_t stream) {
  const float* query = (const float*)d_in[0];
  const float* key_  = (const float*)d_in[1];
  const float* value = (const float*)d_in[2];
  const float* Wq    = (const float*)d_in[3];
  const float* Wk    = (const float*)d_in[4];
  const float* Wv    = (const float*)d_in[5];
  const float* Wo    = (const float*)d_in[6];
  const float* bo    = (const float*)d_in[7];
  const int*   causal = (const int*)d_in[8];
  float* out = (float*)d_out;

  char* ws = (char*)d_ws;
  size_t off = 0;
  auto alloc = [&](size_t bytes) {
    char* p = ws + off;
    off += (bytes + 255) & ~(size_t)255;
    return p;
  };
  const size_t TB = (size_t)MTOT * D_ * sizeof(bf16_t);   // 16 MiB
  bf16_t* qin = (bf16_t*)alloc(TB);    // reused as AO after projections
  bf16_t* kin = (bf16_t*)alloc(TB);
  bf16_t* vin = (bf16_t*)alloc(TB);
  bf16_t* Qp  = (bf16_t*)alloc(TB);
  bf16_t* Kp  = (bf16_t*)alloc(TB);
  bf16_t* Vp  = (bf16_t*)alloc(TB);
  bf16_t* wt  = (bf16_t*)alloc((size_t)3 * D_ * D_ * sizeof(bf16_t));
  bf16_t* wob = (bf16_t*)alloc((size_t)D_ * D_ * sizeof(bf16_t));
  int*    ctr = (int*)alloc(256);
  bf16_t* ao  = qin;   // qin dead after projection GEMM

  hipMemsetAsync(ctr, 0, sizeof(int), stream);

  const int n8 = MTOT * D_ / 8;
  k_cvt<<<2048, 256, 0, stream>>>(query, qin, n8);
  k_cvt<<<2048, 256, 0, stream>>>(key_,  kin, n8);
  k_cvt<<<2048, 256, 0, stream>>>(value, vin, n8);
  k_cvt<<<512, 256, 0, stream>>>(Wo, wob, D_ * D_ / 8);
  k_pack<<<dim3(16, 16, 3), 256, 0, stream>>>(Wq, Wk, Wv, wt);

  k_gemm<0><<<dim3(MTOT / 128, D_ / 128, 3), 256, 0, stream>>>(
      qin, kin, vin, wt, Qp, Kp, Vp, nullptr, nullptr, MTOT, D_, D_);

  k_attn<<<dim3(NPERS, 1), 256, 0, stream>>>(Qp, Kp, Vp, ao, ctr, causal);

  k_gemm<1><<<dim3(MTOT / 128, D_ / 128, 1), 256, 0, stream>>>(
      ao, nullptr, nullptr, wob, nullptr, nullptr, nullptr, out, bo, MTOT, D_, D_);
}